// Round 10
// baseline (178.613 us; speedup 1.0000x reference)
//
#include <hip/hip_runtime.h>
#include <stdint.h>

// ---------------------------------------------------------------------------
// SNN EMNIST forward: T=10, B=4096, IN=784, HID=256, NCLS=47
// R21: take B out of LDS. R20 showed occupancy 22->37.5% with VALUBusy flat
// at 58% -> not issue-bound. Corrected cost model: hash ~31us chip-wide VALU;
// the sticky per-slab cost is the per-CU LDS pipe: B staged via
// global_load_lds (~1150cyc/CU/slab) then ds_read ONCE per byte (~1630cyc)
// + 4.5M bank-conflict cycles. Every staged B byte has exactly one consumer
// lane -> the LDS round-trip is pure overhead.
// Change: swizzle algebra shows the old machinery delivers source quarter
// qd_eff = q to lane (q,c0). So planes are re-laid-out as [kw][n][quarter]
// (splitk index change) and each lane loads its B fragment DIRECTLY
// global->VGPR (bf16x8 deref: 64 lanes cover 64 distinct 16B slots in 1KB =
// fully coalesced; planes L2-resident; latency hides under the hash phase).
// Fragment content bit-identical -> I bitwise identical -> absmax stays
// 4.882812e-4. LDS = 10KB (A dbuf only); one barrier/slab (A-sync only).
// Hoists: 1 x-load/thread/slab (5 tasks share the element);
// adst[s]=adst0+s*1024; tib[s]=tib0+s*6422528. Hash/A-path/MFMA-order/
// epilogue = R20 verbatim.
// ---------------------------------------------------------------------------

#define T_STEPS 10
#define BATCH   4096
#define IN_DIM  784
#define HID     256
#define NCLS    47
#define KWORDS  25                       // ceil(784/32)
#define KPAD    800                      // 25*32

// d_ws layout (bytes):
//   [46039040, ...)  W1{hi,mid,lo} planes: bf16, 409600 B each,
//                    NEW layout [kw][n][quarter]: elem off for (k,n) =
//                    ((kw*256+n)*4 + (k>>3)&3)*8 + (k&7),  kw = k>>5.
#define WS_W1HI_OFF 46039040u
#define WS_W1MD_OFF (46039040u + 409600u)
#define WS_W1LO_OFF (46039040u + 819200u)

typedef __attribute__((ext_vector_type(8))) short    bf16x8;
typedef __attribute__((ext_vector_type(4))) float    f32x4;

__device__ __forceinline__ uint32_t rotl32(uint32_t x, uint32_t r) {
    return __builtin_amdgcn_alignbit(x, x, 32u - r);
}

// JAX threefry2x32, key=(0,42), partitionable scheme: out = o0^o1, x0=0, x1=i.
__device__ __forceinline__ uint32_t tf_hash(uint32_t lo) {
    const uint32_t ks1 = 42u;
    const uint32_t ks2 = 0x1BD11BDAu ^ 42u;
    uint32_t x0 = 0u;
    uint32_t x1 = lo + ks1;
#define TF_RND(r) { x0 += x1; x1 = rotl32(x1, r); x1 ^= x0; }
    TF_RND(13) TF_RND(15) TF_RND(26) TF_RND(6)
    x0 += ks1; x1 += ks2 + 1u;
    TF_RND(17) TF_RND(29) TF_RND(16) TF_RND(24)
    x0 += ks2; x1 += 2u;                       // ks0 == 0
    TF_RND(13) TF_RND(15) TF_RND(26) TF_RND(6)
    x1 += ks1 + 3u;                            // x0 += ks0 is a no-op
    TF_RND(17) TF_RND(29) TF_RND(16) TF_RND(24)
    x0 += ks1; x1 += ks2 + 4u;
    TF_RND(13) TF_RND(15) TF_RND(26) TF_RND(6)
    x0 += ks2; x1 += 5u;                       // ks0 == 0
#undef TF_RND
    return x0 ^ x1;
}

// ---------------------------------------------------------------------------
// Kernel B0: split W1 (f32 [784][256]) into bf16 hi/mid/lo planes in the
// NEW [kw][n][quarter] layout. EXACT: hi+mid+lo == w bitwise. Same split
// math as all passing rounds; only the store index changed.
// ---------------------------------------------------------------------------
__global__ __launch_bounds__(256) void splitk_k(
        const float* __restrict__ W1, ushort* __restrict__ hiT,
        ushort* __restrict__ midT, ushort* __restrict__ loT) {
    int n = blockIdx.x;                  // 0..255
    for (int k = threadIdx.x; k < KPAD; k += 256) {
        float w = (k < IN_DIM) ? W1[k * HID + n] : 0.0f;
        uint32_t u = __float_as_uint(w);
        uint32_t hb = (u + 0x7FFFu + ((u >> 16) & 1u)) >> 16;    // RNE to bf16
        float hf = __uint_as_float(hb << 16);
        float r1 = w - hf;                                       // exact
        uint32_t u1 = __float_as_uint(r1);
        uint32_t mb = (u1 + 0x7FFFu + ((u1 >> 16) & 1u)) >> 16;  // RNE
        float mf2 = __uint_as_float(mb << 16);
        float r2 = r1 - mf2;                                     // exact
        uint32_t u2 = __float_as_uint(r2);
        uint32_t lb = (u2 + 0x7FFFu + ((u2 >> 16) & 1u)) >> 16;  // exact fit
        int kw = k >> 5, qk = (k >> 3) & 3, j = k & 7;
        size_t o = ((size_t)(kw * 256 + n) * 4 + qk) * 8 + j;
        hiT [o] = (ushort)hb;
        midT[o] = (ushort)mb;
        loT [o] = (ushort)lb;
    }
}

// ---------------------------------------------------------------------------
// Fused spikegen + GEMM + LIF scan + readout.
// Block: 80 tile rows (r = t*8 + j) x 256 cols, 512 thr = 8 waves (1M x 8N),
// wave = 80x32 = 5x2 tiles of 16x16x32. Grid 512 = 2+ blocks/CU.
// Per slab: load 6 B frags global->VGPR + A frags ds_read (cur) -> hash
// slab kw+1 (5 x tf_hash, shared x elem) -> ds_write_b16 into A nxt ->
// 30 MFMA -> ONE barrier (A-sync; vmcnt long drained) -> flip.
// LDS: A dbuf 2x5120 = 10KB only.
// ---------------------------------------------------------------------------
#define A_BUFSZ 5120                     // 80 rows x 64B
#define G_LDW   260                      // gbuf row pitch (floats)

__global__ __launch_bounds__(512, 4) void fused_gemm_k(
        const ushort* __restrict__ hiT, const ushort* __restrict__ midT,
        const ushort* __restrict__ loT, const float* __restrict__ b1,
        const float* __restrict__ x, const float* __restrict__ Wr,
        const float* __restrict__ br, float* __restrict__ out) {
    __shared__ __align__(16) char lds[10240];

    const int tid = threadIdx.x;
    const int l   = tid & 63;
    const int wv  = tid >> 6;        // 0..7 = N strip (32 cols each)
    const int b0  = blockIdx.x << 3; // 8 batch rows per block

    f32x4 acc[5][2] = {};

    // A fragment read addressing (A keeps its LDS swizzle, unchanged)
    const int q   = l >> 4;
    const int c0  = l & 15;
    const int sig = q ^ (l & 3) ^ ((l >> 2) & 3);
    const int a_rd = (c0 << 6) + (sig << 4);                 // in A buf

    // B direct-load pointers (lane (q,c0) consumes quarter q of col n):
    // elem off = n*32 + q*8, n = wv*32 + nt*16 + c0; nt adds +512 elems;
    // per-slab bump +8192 elems (16KB).
    const int beoff = ((wv << 5) + c0) * 32 + (q << 3);
    const ushort* bp_hi = hiT  + beoff;
    const ushort* bp_md = midT + beoff;
    const ushort* bp_lo = loT  + beoff;

    // ---- A expansion: 2560 single-element tasks/slab = 5 per thread ----
    // Task s: row = (tid>>5) + 16*s, element eL = tid&31. All 5 tasks share
    // x element (b0+j, k=kw*32+eL): j = (tid>>5)&7 invariant, t = t0 + 2s.
    const int eL   = tid & 31;
    const int row0 = tid >> 5;                 // 0..15
    const int j0   = row0 & 7;
    const int qd0  = ((eL >> 1) >> 2) ^ (row0 & 3) ^ ((row0 >> 2) & 3);
    const int adst0 = (row0 << 6) + (qd0 << 4) + (((eL >> 1) & 3) << 2)
                    + ((eL & 1) << 1);         // + s*1024
    const int xbase = (b0 + j0) * IN_DIM + eL;
    const uint32_t tib0 = (uint32_t)((row0 >> 3) * BATCH + b0 + j0)
                        * (uint32_t)IN_DIM + (uint32_t)eL;  // + s*6422528

// hash slab (koff = slab*32) into A buffer at abase. All 5 compares share
// xv (loaded by caller; 0 on the tail -> compare false -> zero, identical
// to the explicit zero path).
#define HASH_SLAB(koff, abase, xv) \
    _Pragma("unroll") \
    for (int s = 0; s < 5; ++s) { \
        uint32_t h = tf_hash(tib0 + (uint32_t)(s * 6422528) + (uint32_t)(koff)); \
        ushort w_ = ((float)(h >> 9) < (xv) * 8388608.0f) ? (ushort)0x3F80 : (ushort)0; \
        *(ushort*)(lds + (abase) + adst0 + (s << 10)) = w_; \
    }

#define PRELOAD_A(bufidx) \
    const char* A = lds + (bufidx) * A_BUFSZ; \
    bf16x8 af[5]; \
    _Pragma("unroll") \
    for (int mt = 0; mt < 5; ++mt) \
        af[mt] = *(const bf16x8*)(A + a_rd + (mt << 10));

#define LOAD_B \
    bf16x8 bfr[3][2]; \
    _Pragma("unroll") \
    for (int nt = 0; nt < 2; ++nt) { \
        bfr[0][nt] = *(const bf16x8*)(bp_hi + nt * 512); \
        bfr[1][nt] = *(const bf16x8*)(bp_md + nt * 512); \
        bfr[2][nt] = *(const bf16x8*)(bp_lo + nt * 512); \
    } \
    bp_hi += 8192; bp_md += 8192; bp_lo += 8192;

#define MFMA_ALL \
    _Pragma("unroll") \
    for (int nt = 0; nt < 2; ++nt) { \
        _Pragma("unroll") \
        for (int mt = 0; mt < 5; ++mt) { \
            acc[mt][nt] = __builtin_amdgcn_mfma_f32_16x16x32_bf16(af[mt], bfr[0][nt], acc[mt][nt], 0, 0, 0); \
            acc[mt][nt] = __builtin_amdgcn_mfma_f32_16x16x32_bf16(af[mt], bfr[1][nt], acc[mt][nt], 0, 0, 0); \
            acc[mt][nt] = __builtin_amdgcn_mfma_f32_16x16x32_bf16(af[mt], bfr[2][nt], acc[mt][nt], 0, 0, 0); \
        } \
    }

    // ---- prologue: hash slab 0 into A buffer 0 ----
    {
        float xv0 = x[xbase];            // eL < 32 < 784: always in bounds
        HASH_SLAB(0, 0, xv0)
    }
    __syncthreads();

    int cur = 0;
#pragma unroll 1
    for (int kw = 0; kw < KWORDS; ++kw) {
        // (1) B frags for slab kw: direct global->VGPR, coalesced 1KB/wave;
        //     latency hides under the hash below.
        LOAD_B
        // (2) A frags for slab kw (ds_read; A-cur ready since last barrier)
        PRELOAD_A(cur)
        // (3) hash slab kw+1 into A nxt (x elem loaded once; tail -> 0)
        if (kw < KWORDS - 1) {
            const int koff = (kw + 1) << 5;
            float xv = 0.0f;
            if (!(kw == KWORDS - 2 && eL >= 16))   // guards x OOB on tail
                xv = x[xbase + koff];
            HASH_SLAB(koff, (cur ^ 1) * A_BUFSZ, xv)
        }
        // (4) 30 MFMA (af via lgkm, bfr via vmcnt — both long in flight)
        MFMA_ALL

        __syncthreads();   // A-nxt visible; vmcnt/lgkm naturally drained
        cur ^= 1;
    }
#undef HASH_SLAB
#undef PRELOAD_A
#undef LOAD_B
#undef MFMA_ALL

    // =======================================================================
    // Epilogue (R20 verbatim): LIF scan via lane-pair exchange + readout.
    // acc[mt][nt][rr] = I(t = 2*mt + (q>>1), j = (q&1)*4+rr,
    //                     col = wv*32 + nt*16 + c0).  Partner lane = l ^ 32.
    // =======================================================================
    float b1v[2];
#pragma unroll
    for (int nt = 0; nt < 2; ++nt)
        b1v[nt] = b1[(wv << 5) + (nt << 4) + c0];

    float av[5][2][4];
#pragma unroll
    for (int mt = 0; mt < 5; ++mt)
#pragma unroll
        for (int nt = 0; nt < 2; ++nt)
#pragma unroll
            for (int rr = 0; rr < 4; ++rr)
                av[mt][nt][rr] = acc[mt][nt][rr] + b1v[nt];

    const int qh = q >> 1;               // 0: holds even t; 1: holds odd t
    float g[2][4];
#pragma unroll
    for (int nt = 0; nt < 2; ++nt) {
#pragma unroll
        for (int rr = 0; rr < 4; ++rr) {
            float v = 0.f, ga = 0.f, wt = 0.0009765625f;   // 2^-10
#pragma unroll
            for (int m = 0; m < 5; ++m) {
                float pv = __shfl_xor(av[m][nt][rr], 32);  // partner's value
                float Ie = qh ? pv : av[m][nt][rr];        // t = 2m
                float Io = qh ? av[m][nt][rr] : pv;        // t = 2m+1
                v = v + (Ie - v) * 0.5f;
                if (v >= 1.0f) { ga += wt; v = 0.f; }
                wt += wt;
                v = v + (Io - v) * 0.5f;
                if (v >= 1.0f) { ga += wt; v = 0.f; }
                wt += wt;
            }
            g[nt][rr] = ga;
        }
    }

    float* gbuf = (float*)lds;           // [8][G_LDW] = 8320 B; K-loop done
    if (l < 32) {                        // qh==0 lanes hold canonical g
#pragma unroll
        for (int nt = 0; nt < 2; ++nt)
#pragma unroll
            for (int rr = 0; rr < 4; ++rr) {
                int jj  = ((q & 1) << 2) + rr;
                int col = (wv << 5) + (nt << 4) + c0;
                gbuf[jj * G_LDW + col] = g[nt][rr];
            }
    }
    __syncthreads();

    {   // readout: wave wv -> batch row b0+wv; identical fmaf chain
        const int c = l;
        if (c < NCLS) {
            const float* gb = &gbuf[wv * G_LDW];
            float a = 0.f;
            for (int h4 = 0; h4 < 64; ++h4) {
                float w0 = Wr[((h4 << 2) + 0) * NCLS + c];
                float w1 = Wr[((h4 << 2) + 1) * NCLS + c];
                float w2 = Wr[((h4 << 2) + 2) * NCLS + c];
                float w3 = Wr[((h4 << 2) + 3) * NCLS + c];
                float4 gg = *(const float4*)&gb[h4 << 2];
                a = fmaf(gg.x, w0, a);
                a = fmaf(gg.y, w1, a);
                a = fmaf(gg.z, w2, a);
                a = fmaf(gg.w, w3, a);
            }
            out[(b0 + wv) * NCLS + c] = a + br[c] * 0.9990234375f;
        }
    }
}

extern "C" void kernel_launch(void* const* d_in, const int* in_sizes, int n_in,
                              void* d_out, int out_size, void* d_ws, size_t ws_size,
                              hipStream_t stream) {
    const float* x  = (const float*)d_in[0];
    const float* W1 = (const float*)d_in[1];
    const float* b1 = (const float*)d_in[2];
    const float* Wr = (const float*)d_in[3];
    const float* br = (const float*)d_in[4];
    float* out = (float*)d_out;

    ushort* w1hi  = (ushort*)((char*)d_ws + WS_W1HI_OFF);
    ushort* w1md  = (ushort*)((char*)d_ws + WS_W1MD_OFF);
    ushort* w1lo  = (ushort*)((char*)d_ws + WS_W1LO_OFF);

    splitk_k<<<HID, 256, 0, stream>>>(W1, w1hi, w1md, w1lo);
    fused_gemm_k<<<BATCH / 8, 512, 0, stream>>>(w1hi, w1md, w1lo, b1, x,
                                                Wr, br, out);
}